// Round 2
// 607.296 us; speedup vs baseline: 1.0132x; 1.0132x over previous
//
#include <hip/hip_runtime.h>
#include <hip/hip_bf16.h>
#include <stdint.h>

typedef short short8 __attribute__((ext_vector_type(8)));
typedef float f32x4  __attribute__((ext_vector_type(4)));

typedef __attribute__((address_space(1))) uint32_t u32_g;
typedef __attribute__((address_space(3))) uint32_t u32_l;

#define BM 256
#define BN 256
#define BK 32
#define SLOTB 32768   // per ring slot: A 16 KiB + B 16 KiB
#define BOFF  16384   // B region offset within a slot

// async global->LDS, 16B/lane. LDS dest = wave-uniform base + lane*16 (we pass
// per-lane ptrs that satisfy base+lane*16; HW takes firstlane as base).
__device__ __forceinline__ void gld_lds16(const void* g, const void* l) {
  __builtin_amdgcn_global_load_lds((u32_g*)(uintptr_t)g, (u32_l*)(uintptr_t)l, 16, 0, 0);
}

// ---------------------------------------------------------------------------
// GEMM: C = epilogue(A[M,K](bf16) @ BT[N,K](bf16)^T + bias(fp32))
// 256x256 tile, 8 waves (wave tile 128x64), BK=32, 3-slot LDS ring,
// counted vmcnt(4) across raw barriers (T3+T4), setprio around MFMA (T5).
// FINAL=0: leaky-relu -> bf16 Cb (stride 2048)
// FINAL=1: diag-abs + triangle scatter -> fp32 Cf[(r*64+c)*8192 + m],
//          plus zero-store to the mirrored lower-triangle slot (replaces memset)
// ---------------------------------------------------------------------------
template <int FINAL>
__global__ __launch_bounds__(512, 2) void gemm_k(
    const __hip_bfloat16* __restrict__ A,
    const __hip_bfloat16* __restrict__ BT,
    const float* __restrict__ bias,
    __hip_bfloat16* __restrict__ Cb,
    float* __restrict__ Cf,
    const int* __restrict__ tbl,
    int K, int Nreal)
{
  __shared__ __attribute__((aligned(16))) char smem[3 * SLOTB];

  const int tid  = threadIdx.x;
  const int lane = tid & 63;
  const int l15  = lane & 15;
  const int quad = lane >> 4;
  const int wave = tid >> 6;
  const int wm   = (wave >> 2) * 128;   // wave row offset in 256-tile
  const int wn   = (wave & 3) * 64;     // wave col offset

  const int bm = blockIdx.x * BM;
  const int bn = blockIdx.y * BN;

  // ds_read base offsets. Row = 32 bf16 = 4 chunks of 16B; chunk c of row r
  // lives at slot (c + (r>>1)) & 3  -> uniform 8 lanes per 4-bank group on
  // ds_read_b128 (2-way aliasing = free). The swizzle slot is per-thread
  // constant across i/j (i*16 rows shift (r>>1) by multiples of 4).
  const int arow = wm + l15;
  const uint32_t aoff = (uint32_t)arow * 64u + (uint32_t)(((quad + (arow >> 1)) & 3) << 4);
  const int brow = wn + l15;
  const uint32_t boff = BOFF + (uint32_t)brow * 64u + (uint32_t)(((quad + (brow >> 1)) & 3) << 4);

  // Staging: tile = 256 rows x 32 bf16 (64B) per matrix = 2 x 8KiB insts each.
  // LDS dest linear (ci*16); global source chunk pre-inverse-swizzled.
  const __hip_bfloat16* ag[2];
  const __hip_bfloat16* bg[2];
  uint32_t dA[2], dB[2];
#pragma unroll
  for (int c = 0; c < 2; ++c) {
    int ci  = tid + 512 * c;           // 0..1023
    int row = ci >> 2;                 // 0..255
    int gc  = ((ci & 3) - (row >> 1)) & 3;
    ag[c] = A  + (size_t)(bm + row) * K + gc * 8;
    bg[c] = BT + (size_t)(bn + row) * K + gc * 8;
    dA[c] = (uint32_t)ci * 16u;
    dB[c] = BOFF + (uint32_t)ci * 16u;
  }

  f32x4 acc[8][4];
#pragma unroll
  for (int i = 0; i < 8; ++i)
#pragma unroll
    for (int j = 0; j < 4; ++j)
      acc[i][j] = (f32x4){0.f, 0.f, 0.f, 0.f};

  const int nk = K >> 5;

  // prologue: stage tile0 -> slot0, tile1 -> slot1 (8 loads in flight)
#pragma unroll
  for (int t = 0; t < 2; ++t) {
    char* stb = smem + t * SLOTB;
#pragma unroll
    for (int c = 0; c < 2; ++c) {
      gld_lds16(ag[c], stb + dA[c]);
      gld_lds16(bg[c], stb + dB[c]);
      ag[c] += BK;
      bg[c] += BK;
    }
  }

  int cur = 0, nst = 2;
  for (int kt = 0; kt < nk; ++kt) {
    // vmcnt(4): tile kt's 4 loads (issued 2 iterations ago) complete; tile
    // kt+1's 4 stay in flight across the barrier. lgkmcnt(0): all my ds_reads
    // of the slot being recycled are retired before anyone overwrites it.
    if (kt < nk - 1) asm volatile("s_waitcnt vmcnt(4) lgkmcnt(0)" ::: "memory");
    else             asm volatile("s_waitcnt vmcnt(0) lgkmcnt(0)" ::: "memory");
    __builtin_amdgcn_s_barrier();
    asm volatile("" ::: "memory");

    const char* rb  = smem + cur * SLOTB;
    char*       stb = smem + nst * SLOTB;

    // Issue next-next tile's staging FIRST (template order: STAGE before
    // ds_read+MFMA) -- 4 loads go in flight under this iteration's compute.
    if (kt < nk - 2) {
#pragma unroll
      for (int c = 0; c < 2; ++c) {
        gld_lds16(ag[c], stb + dA[c]);
        gld_lds16(bg[c], stb + dB[c]);
        ag[c] += BK;
        bg[c] += BK;
      }
    }

    // cluster 1: B frags + A rows 0..63, 16 MFMA
    short8 bf[4], af[4];
#pragma unroll
    for (int j = 0; j < 4; ++j) bf[j] = *(const short8*)(rb + boff + j * 1024);
#pragma unroll
    for (int i = 0; i < 4; ++i) af[i] = *(const short8*)(rb + aoff + i * 1024);
    __builtin_amdgcn_s_setprio(1);
#pragma unroll
    for (int i = 0; i < 4; ++i)
#pragma unroll
      for (int j = 0; j < 4; ++j)
        acc[i][j] = __builtin_amdgcn_mfma_f32_16x16x32_bf16(af[i], bf[j], acc[i][j], 0, 0, 0);
    __builtin_amdgcn_s_setprio(0);

    // cluster 2: A rows 64..127, 16 MFMA
    short8 af2[4];
#pragma unroll
    for (int i = 0; i < 4; ++i) af2[i] = *(const short8*)(rb + aoff + 4096 + i * 1024);
    __builtin_amdgcn_s_setprio(1);
#pragma unroll
    for (int i = 0; i < 4; ++i)
#pragma unroll
      for (int j = 0; j < 4; ++j)
        acc[i + 4][j] = __builtin_amdgcn_mfma_f32_16x16x32_bf16(af2[i], bf[j], acc[i + 4][j], 0, 0, 0);
    __builtin_amdgcn_s_setprio(0);

    cur = (cur == 2) ? 0 : cur + 1;
    nst = (nst == 2) ? 0 : nst + 1;
  }

  // Epilogue. C/D layout: col = lane&15, row = quad*4 + reg (m89-verified).
  if (FINAL == 0) {
#pragma unroll
    for (int j = 0; j < 4; ++j) {
      int   n  = bn + wn + j * 16 + l15;
      float bv = bias[n];
#pragma unroll
      for (int i = 0; i < 8; ++i) {
        int m0 = bm + wm + i * 16 + quad * 4;
#pragma unroll
        for (int r = 0; r < 4; ++r) {
          float v = acc[i][j][r] + bv;
          v = (v > 0.f) ? v : 0.01f * v;
          Cb[(size_t)(m0 + r) * 2048 + n] = __float2bfloat16(v);
        }
      }
    }
  } else {
#pragma unroll
    for (int j = 0; j < 4; ++j) {
      int n = bn + wn + j * 16 + l15;
      if (n < Nreal) {
        float bv   = bias[n];
        int  code  = tbl[n];
        int  dst   = code & 4095;          // r*64 + c (upper triangle)
        bool diag  = (code & 4096) != 0;
        int  mir   = ((dst & 63) << 6) | (dst >> 6);  // (c,r) lower mirror
        const f32x4 z = (f32x4){0.f, 0.f, 0.f, 0.f};
#pragma unroll
        for (int i = 0; i < 8; ++i) {
          int m0 = bm + wm + i * 16 + quad * 4;
          f32x4 pk;
#pragma unroll
          for (int r = 0; r < 4; ++r) {
            float v = acc[i][j][r] + bv;
            if (diag) v = fabsf(v);
            pk[r] = v;
          }
          *reinterpret_cast<f32x4*>(Cf + (size_t)dst * 8192 + m0) = pk;
          if (!diag)  // strict-upper (r,c) <-> strict-lower (c,r) is a bijection:
            *reinterpret_cast<f32x4*>(Cf + (size_t)mir * 8192 + m0) = z;
        }
      }
    }
  }
}

// ---------------------------------------------------------------------------
// Weight transpose + fp32->bf16: in[K,N](f32) -> out[NP,K](bf16), rows >= N zero
// ---------------------------------------------------------------------------
__global__ void transpose_k(const float* __restrict__ in,
                            __hip_bfloat16* __restrict__ out,
                            int K, int N)
{
  __shared__ __hip_bfloat16 t[32][33];
  const int n0 = blockIdx.x * 32;
  const int k0 = blockIdx.y * 32;
  const int tx = threadIdx.x, ty = threadIdx.y;
  const __hip_bfloat16 zero = __float2bfloat16(0.f);
#pragma unroll
  for (int r = 0; r < 32; r += 8) {
    int k = k0 + ty + r, n = n0 + tx;
    t[ty + r][tx] = (n < N) ? __float2bfloat16(in[(size_t)k * N + n]) : zero;
  }
  __syncthreads();
#pragma unroll
  for (int r = 0; r < 32; r += 8) {
    int n = n0 + ty + r;
    out[(size_t)n * K + k0 + tx] = t[tx][ty + r];
  }
}

// fp32 -> bf16 elementwise (x), 4 per thread
__global__ void cvt_k(const float* __restrict__ in,
                      __hip_bfloat16* __restrict__ out, int n)
{
  int i = (blockIdx.x * 256 + threadIdx.x) * 4;
  if (i >= n) return;
  float4 v = *reinterpret_cast<const float4*>(in + i);
  union { unsigned short us[4]; uint2 v2; } pk;
  __hip_bfloat16 h;
  h = __float2bfloat16(v.x); pk.us[0] = *reinterpret_cast<unsigned short*>(&h);
  h = __float2bfloat16(v.y); pk.us[1] = *reinterpret_cast<unsigned short*>(&h);
  h = __float2bfloat16(v.z); pk.us[2] = *reinterpret_cast<unsigned short*>(&h);
  h = __float2bfloat16(v.w); pk.us[3] = *reinterpret_cast<unsigned short*>(&h);
  *reinterpret_cast<uint2*>(out + i) = pk.v2;
}

// l -> (r,c) scatter table. Row r covers cols 63..r; diag (c==r) flagged bit 12.
__global__ void table_k(int* __restrict__ tbl)
{
  int l = blockIdx.x * 64 + threadIdx.x;
  if (l >= 2080) return;
  int r = 0, s = 0;
  while (s + (64 - r) <= l) { s += 64 - r; ++r; }
  int c = 63 - (l - s);
  tbl[l] = (r * 64 + c) | ((r == c) ? 4096 : 0);
}

extern "C" void kernel_launch(void* const* d_in, const int* in_sizes, int n_in,
                              void* d_out, int out_size, void* d_ws, size_t ws_size,
                              hipStream_t stream)
{
  const float* x   = (const float*)d_in[0];
  const float* W1  = (const float*)d_in[1];
  const float* b1  = (const float*)d_in[2];
  const float* W2  = (const float*)d_in[3];
  const float* b2  = (const float*)d_in[4];
  const float* W21 = (const float*)d_in[5];
  const float* b21 = (const float*)d_in[6];
  const float* W22 = (const float*)d_in[7];
  const float* b22 = (const float*)d_in[8];
  const float* W3  = (const float*)d_in[9];
  const float* b3  = (const float*)d_in[10];
  float* out = (float*)d_out;

  char* ws = (char*)d_ws;
  __hip_bfloat16* act0 = (__hip_bfloat16*)(ws);                         // 8192x2048 bf16
  __hip_bfloat16* act1 = (__hip_bfloat16*)(ws + ((size_t)32 << 20));    // 8192x2048 bf16
  __hip_bfloat16* xb   = act1;                                          // 8192x1024 bf16 (dead after GEMM1)
  __hip_bfloat16* W1T  = (__hip_bfloat16*)(ws + ((size_t)64 << 20));    // 2048x1024
  __hip_bfloat16* W2T  = (__hip_bfloat16*)(ws + ((size_t)68 << 20));    // 2048x2048
  __hip_bfloat16* W21T = (__hip_bfloat16*)(ws + ((size_t)76 << 20));    // 2048x2048
  __hip_bfloat16* W22T = (__hip_bfloat16*)(ws + ((size_t)84 << 20));    // 2048x2048
  __hip_bfloat16* W3T  = (__hip_bfloat16*)(ws + ((size_t)92 << 20));    // 2304x2048 (zero-padded) = 9 MiB
  int*            tbl  = (int*)(ws + ((size_t)101 << 20));              // 2080 ints

  // No output memset: FINAL gemm writes every (r,c,m) -- upper from the GEMM,
  // strict-lower as explicit zeros (mirror of strict-upper).
  table_k<<<33, 64, 0, stream>>>(tbl);

  cvt_k<<<8192, 256, 0, stream>>>(x, xb, 8192 * 1024);

  dim3 tb(32, 8);
  transpose_k<<<dim3(64, 32), tb, 0, stream>>>(W1,  W1T,  1024, 2048);
  transpose_k<<<dim3(64, 64), tb, 0, stream>>>(W2,  W2T,  2048, 2048);
  transpose_k<<<dim3(64, 64), tb, 0, stream>>>(W21, W21T, 2048, 2048);
  transpose_k<<<dim3(64, 64), tb, 0, stream>>>(W22, W22T, 2048, 2048);
  transpose_k<<<dim3(72, 64), tb, 0, stream>>>(W3,  W3T,  2048, 2080); // rows 2080..2303 zero

  gemm_k<0><<<dim3(32, 8), 512, 0, stream>>>(xb,   W1T,  b1,  act0, nullptr, nullptr, 1024, 2048);
  gemm_k<0><<<dim3(32, 8), 512, 0, stream>>>(act0, W2T,  b2,  act1, nullptr, nullptr, 2048, 2048);
  gemm_k<0><<<dim3(32, 8), 512, 0, stream>>>(act1, W21T, b21, act0, nullptr, nullptr, 2048, 2048);
  gemm_k<0><<<dim3(32, 8), 512, 0, stream>>>(act0, W22T, b22, act1, nullptr, nullptr, 2048, 2048);
  gemm_k<1><<<dim3(32, 9), 512, 0, stream>>>(act1, W3T,  b3,  nullptr, out,  tbl,     2048, 2080);
}